// Round 1
// baseline (535.318 us; speedup 1.0000x reference)
//
#include <hip/hip_runtime.h>
#include <math.h>

constexpr int NN = 100000;   // nodes
constexpr int NE = 1250000;  // edges
constexpr int NF = 64;       // input features
constexpr int NH = 16;       // hidden
constexpr int NC = 7;        // classes

// ---------------- Kernel 1: y = x @ W1 ; A = y, B = y + b1 ----------------
__global__ __launch_bounds__(256) void k1_gemm(
    const float* __restrict__ x, const float* __restrict__ W1,
    const float* __restrict__ b1, float* __restrict__ A, float* __restrict__ B) {
    __shared__ float w[NF * NH];   // 4 KB
    __shared__ float bias[NH];
    for (int i = threadIdx.x; i < NF * NH; i += blockDim.x) w[i] = W1[i];
    if (threadIdx.x < NH) bias[threadIdx.x] = b1[threadIdx.x];
    __syncthreads();
    int node = blockIdx.x * blockDim.x + threadIdx.x;
    if (node >= NN) return;

    float acc[NH];
#pragma unroll
    for (int j = 0; j < NH; ++j) acc[j] = 0.f;

    const float4* xr = (const float4*)(x + (size_t)node * NF);
#pragma unroll
    for (int k4 = 0; k4 < NF / 4; ++k4) {
        float4 xv = xr[k4];
        int k = k4 * 4;
#pragma unroll
        for (int j = 0; j < NH; ++j) {
            acc[j] += xv.x * w[(k + 0) * NH + j]
                    + xv.y * w[(k + 1) * NH + j]
                    + xv.z * w[(k + 2) * NH + j]
                    + xv.w * w[(k + 3) * NH + j];
        }
    }
    float4* Ar = (float4*)(A + (size_t)node * NH);
    float4* Br = (float4*)(B + (size_t)node * NH);
#pragma unroll
    for (int q = 0; q < NH / 4; ++q) {
        float4 a;
        a.x = acc[q * 4 + 0]; a.y = acc[q * 4 + 1];
        a.z = acc[q * 4 + 2]; a.w = acc[q * 4 + 3];
        Ar[q] = a;
        float4 bv;
        bv.x = a.x + bias[q * 4 + 0]; bv.y = a.y + bias[q * 4 + 1];
        bv.z = a.z + bias[q * 4 + 2]; bv.w = a.w + bias[q * 4 + 3];
        Br[q] = bv;
    }
}

// ------------- Kernel 2: B[dst] += A[src]  (4 threads per edge) -------------
__global__ __launch_bounds__(256) void k2_agg(
    const float* __restrict__ A, float* __restrict__ B,
    const int* __restrict__ src, const int* __restrict__ dst) {
    int t = blockIdx.x * blockDim.x + threadIdx.x;
    int e = t >> 2;
    if (e >= NE) return;
    int f = (t & 3) * 4;
    int s = src[e];
    int d = dst[e];
    float4 v = *(const float4*)(A + (size_t)s * NH + f);
    float* bp = B + (size_t)d * NH + f;
    atomicAdd(bp + 0, v.x);
    atomicAdd(bp + 1, v.y);
    atomicAdd(bp + 2, v.z);
    atomicAdd(bp + 3, v.w);
}

// --- Kernel 3: h=relu(B); t=relu(h@W2+b2); z=t@W3; A=z, B=z+b3 (in place) ---
__global__ __launch_bounds__(256) void k3_mid(
    float* __restrict__ A, float* __restrict__ B,
    const float* __restrict__ W2, const float* __restrict__ b2,
    const float* __restrict__ W3, const float* __restrict__ b3) {
    __shared__ float w2[NH * NH], w3[NH * NH];
    __shared__ float bb2[NH], bb3[NH];
    for (int i = threadIdx.x; i < NH * NH; i += blockDim.x) {
        w2[i] = W2[i];
        w3[i] = W3[i];
    }
    if (threadIdx.x < NH) {
        bb2[threadIdx.x] = b2[threadIdx.x];
        bb3[threadIdx.x] = b3[threadIdx.x];
    }
    __syncthreads();
    int node = blockIdx.x * blockDim.x + threadIdx.x;
    if (node >= NN) return;

    float h[NH];
    float4* Brow = (float4*)(B + (size_t)node * NH);
#pragma unroll
    for (int q = 0; q < 4; ++q) {
        float4 v = Brow[q];
        h[q * 4 + 0] = fmaxf(v.x, 0.f);
        h[q * 4 + 1] = fmaxf(v.y, 0.f);
        h[q * 4 + 2] = fmaxf(v.z, 0.f);
        h[q * 4 + 3] = fmaxf(v.w, 0.f);
    }
    float t[NH];
#pragma unroll
    for (int j = 0; j < NH; ++j) t[j] = bb2[j];
#pragma unroll
    for (int k = 0; k < NH; ++k) {
        float hk = h[k];
#pragma unroll
        for (int j = 0; j < NH; ++j) t[j] += hk * w2[k * NH + j];
    }
#pragma unroll
    for (int j = 0; j < NH; ++j) t[j] = fmaxf(t[j], 0.f);

    float z[NH];
#pragma unroll
    for (int j = 0; j < NH; ++j) z[j] = 0.f;
#pragma unroll
    for (int k = 0; k < NH; ++k) {
        float tk = t[k];
#pragma unroll
        for (int j = 0; j < NH; ++j) z[j] += tk * w3[k * NH + j];
    }
    float4* Arow = (float4*)(A + (size_t)node * NH);
#pragma unroll
    for (int q = 0; q < 4; ++q) {
        float4 a;
        a.x = z[q * 4 + 0]; a.y = z[q * 4 + 1];
        a.z = z[q * 4 + 2]; a.w = z[q * 4 + 3];
        Arow[q] = a;
        float4 bv;
        bv.x = a.x + bb3[q * 4 + 0]; bv.y = a.y + bb3[q * 4 + 1];
        bv.z = a.z + bb3[q * 4 + 2]; bv.w = a.w + bb3[q * 4 + 3];
        Brow[q] = bv;
    }
}

// ---- Kernel 5: h=relu(B); o=h@W4+b4; out = log_softmax(o) ----
__global__ __launch_bounds__(256) void k5_out(
    const float* __restrict__ B, const float* __restrict__ W4,
    const float* __restrict__ b4, float* __restrict__ out) {
    __shared__ float w4[NH * NC];
    __shared__ float bb4[NC];
    for (int i = threadIdx.x; i < NH * NC; i += blockDim.x) w4[i] = W4[i];
    if (threadIdx.x < NC) bb4[threadIdx.x] = b4[threadIdx.x];
    __syncthreads();
    int node = blockIdx.x * blockDim.x + threadIdx.x;
    if (node >= NN) return;

    float h[NH];
    const float4* Brow = (const float4*)(B + (size_t)node * NH);
#pragma unroll
    for (int q = 0; q < 4; ++q) {
        float4 v = Brow[q];
        h[q * 4 + 0] = fmaxf(v.x, 0.f);
        h[q * 4 + 1] = fmaxf(v.y, 0.f);
        h[q * 4 + 2] = fmaxf(v.z, 0.f);
        h[q * 4 + 3] = fmaxf(v.w, 0.f);
    }
    float o[NC];
#pragma unroll
    for (int c = 0; c < NC; ++c) o[c] = bb4[c];
#pragma unroll
    for (int k = 0; k < NH; ++k) {
        float hk = h[k];
#pragma unroll
        for (int c = 0; c < NC; ++c) o[c] += hk * w4[k * NC + c];
    }
    float m = o[0];
#pragma unroll
    for (int c = 1; c < NC; ++c) m = fmaxf(m, o[c]);
    float s = 0.f;
#pragma unroll
    for (int c = 0; c < NC; ++c) s += expf(o[c] - m);
    float ls = m + logf(s);
    float* op = out + (size_t)node * NC;
#pragma unroll
    for (int c = 0; c < NC; ++c) op[c] = o[c] - ls;
}

extern "C" void kernel_launch(void* const* d_in, const int* in_sizes, int n_in,
                              void* d_out, int out_size, void* d_ws, size_t ws_size,
                              hipStream_t stream) {
    const float* x  = (const float*)d_in[0];
    const int*   ei = (const int*)d_in[1];   // [2, NE] flat: src then dst
    const float* W1 = (const float*)d_in[2];
    const float* b1 = (const float*)d_in[3];
    const float* W2 = (const float*)d_in[4];
    const float* b2 = (const float*)d_in[5];
    const float* W3 = (const float*)d_in[6];
    const float* b3 = (const float*)d_in[7];
    const float* W4 = (const float*)d_in[8];
    const float* b4 = (const float*)d_in[9];
    float* out = (float*)d_out;

    float* A = (float*)d_ws;                   // [NN, NH] gather source
    float* B = A + (size_t)NN * NH;            // [NN, NH] scatter target
    const int* src = ei;
    const int* dst = ei + NE;

    const int nodeBlocks = (NN + 255) / 256;
    const int edgeBlocks = (NE * 4 + 255) / 256;

    k1_gemm<<<nodeBlocks, 256, 0, stream>>>(x, W1, b1, A, B);
    k2_agg<<<edgeBlocks, 256, 0, stream>>>(A, B, src, dst);
    k3_mid<<<nodeBlocks, 256, 0, stream>>>(A, B, W2, b2, W3, b3);
    k2_agg<<<edgeBlocks, 256, 0, stream>>>(A, B, src, dst);
    k5_out<<<nodeBlocks, 256, 0, stream>>>(B, W4, b4, out);
}

// Round 2
// 234.956 us; speedup vs baseline: 2.2784x; 2.2784x over previous
//
#include <hip/hip_runtime.h>
#include <math.h>

constexpr int NN = 100000;   // nodes
constexpr int NE = 1250000;  // edges
constexpr int NF = 64;       // input features
constexpr int NH = 16;       // hidden
constexpr int NC = 7;        // classes
constexpr int SCAN_B = (NN + 255) / 256;   // 391 scan blocks

// ---------------- Kernel 1: y = x @ W1 ; A = y, B = y + b1 ----------------
__global__ __launch_bounds__(256) void k1_gemm(
    const float* __restrict__ x, const float* __restrict__ W1,
    const float* __restrict__ b1, float* __restrict__ A, float* __restrict__ B) {
    __shared__ float w[NF * NH];   // 4 KB
    __shared__ float bias[NH];
    for (int i = threadIdx.x; i < NF * NH; i += blockDim.x) w[i] = W1[i];
    if (threadIdx.x < NH) bias[threadIdx.x] = b1[threadIdx.x];
    __syncthreads();
    int node = blockIdx.x * blockDim.x + threadIdx.x;
    if (node >= NN) return;

    float acc[NH];
#pragma unroll
    for (int j = 0; j < NH; ++j) acc[j] = 0.f;

    const float4* xr = (const float4*)(x + (size_t)node * NF);
#pragma unroll
    for (int k4 = 0; k4 < NF / 4; ++k4) {
        float4 xv = xr[k4];
        int k = k4 * 4;
#pragma unroll
        for (int j = 0; j < NH; ++j) {
            acc[j] += xv.x * w[(k + 0) * NH + j]
                    + xv.y * w[(k + 1) * NH + j]
                    + xv.z * w[(k + 2) * NH + j]
                    + xv.w * w[(k + 3) * NH + j];
        }
    }
    float4* Ar = (float4*)(A + (size_t)node * NH);
    float4* Br = (float4*)(B + (size_t)node * NH);
#pragma unroll
    for (int q = 0; q < NH / 4; ++q) {
        float4 a;
        a.x = acc[q * 4 + 0]; a.y = acc[q * 4 + 1];
        a.z = acc[q * 4 + 2]; a.w = acc[q * 4 + 3];
        Ar[q] = a;
        float4 bv;
        bv.x = a.x + bias[q * 4 + 0]; bv.y = a.y + bias[q * 4 + 1];
        bv.z = a.z + bias[q * 4 + 2]; bv.w = a.w + bias[q * 4 + 3];
        Br[q] = bv;
    }
}

// ---------------- CSR build: degree histogram ----------------
__global__ __launch_bounds__(256) void k_deg(
    const int* __restrict__ dst, int* __restrict__ deg) {
    int e = blockIdx.x * 256 + threadIdx.x;
    if (e < NE) atomicAdd(&deg[dst[e]], 1);
}

// block-wise inclusive scan; emit per-block totals
__global__ __launch_bounds__(256) void k_scan_part(
    const int* __restrict__ deg, int* __restrict__ incl, int* __restrict__ bsum) {
    __shared__ int s[256];
    int i = blockIdx.x * 256 + threadIdx.x;
    int v = (i < NN) ? deg[i] : 0;
    s[threadIdx.x] = v;
    __syncthreads();
    for (int d = 1; d < 256; d <<= 1) {
        int t = (threadIdx.x >= d) ? s[threadIdx.x - d] : 0;
        __syncthreads();
        s[threadIdx.x] += t;
        __syncthreads();
    }
    if (i < NN) incl[i] = s[threadIdx.x];
    if (threadIdx.x == 255) bsum[blockIdx.x] = s[255];
}

// single-block exclusive scan of the 391 block totals
__global__ __launch_bounds__(512) void k_scan_block(
    const int* __restrict__ bsum, int* __restrict__ boff) {
    __shared__ int s[512];
    int t = threadIdx.x;
    int v = (t < SCAN_B) ? bsum[t] : 0;
    s[t] = v;
    __syncthreads();
    for (int d = 1; d < 512; d <<= 1) {
        int u = (t >= d) ? s[t - d] : 0;
        __syncthreads();
        s[t] += u;
        __syncthreads();
    }
    if (t < SCAN_B) boff[t] = s[t] - v;   // exclusive
}

// off[i] = exclusive scan; cur[i] = off[i] (fill cursor)
__global__ __launch_bounds__(256) void k_scan_final(
    const int* __restrict__ incl, const int* __restrict__ deg,
    const int* __restrict__ boff, int* __restrict__ off, int* __restrict__ cur) {
    int i = blockIdx.x * 256 + threadIdx.x;
    if (i < NN) {
        int e = incl[i] - deg[i] + boff[blockIdx.x];
        off[i] = e;
        cur[i] = e;
    }
}

// ticketed CSR fill: csr[pos] = src  (grouped by dst)
__global__ __launch_bounds__(256) void k_fill(
    const int* __restrict__ src, const int* __restrict__ dst,
    int* __restrict__ cur, int* __restrict__ csr) {
    int e = blockIdx.x * 256 + threadIdx.x;
    if (e < NE) {
        int d = dst[e];
        int pos = atomicAdd(&cur[d], 1);
        csr[pos] = src[e];
    }
}

// ---------------- gather aggregation: B[n] += sum_{s in N(n)} A[s] ----------------
__global__ __launch_bounds__(256) void k_gather(
    const float* __restrict__ A, float* __restrict__ B,
    const int* __restrict__ off, const int* __restrict__ deg,
    const int* __restrict__ csr) {
    int t = blockIdx.x * 256 + threadIdx.x;
    int n = t >> 2;
    if (n >= NN) return;
    int q = (t & 3) * 4;
    int o = off[n], dg = deg[n];
    float4 a0 = {0.f, 0.f, 0.f, 0.f}, a1 = {0.f, 0.f, 0.f, 0.f};
    int j = 0;
    for (; j + 2 <= dg; j += 2) {
        int s0 = csr[o + j];
        int s1 = csr[o + j + 1];
        float4 v0 = *(const float4*)(A + (size_t)s0 * NH + q);
        float4 v1 = *(const float4*)(A + (size_t)s1 * NH + q);
        a0.x += v0.x; a0.y += v0.y; a0.z += v0.z; a0.w += v0.w;
        a1.x += v1.x; a1.y += v1.y; a1.z += v1.z; a1.w += v1.w;
    }
    if (j < dg) {
        int s0 = csr[o + j];
        float4 v0 = *(const float4*)(A + (size_t)s0 * NH + q);
        a0.x += v0.x; a0.y += v0.y; a0.z += v0.z; a0.w += v0.w;
    }
    float4* bp = (float4*)(B + (size_t)n * NH + q);
    float4 b = *bp;
    b.x += a0.x + a1.x; b.y += a0.y + a1.y;
    b.z += a0.z + a1.z; b.w += a0.w + a1.w;
    *bp = b;
}

// --- Kernel 3: h=relu(B); t=relu(h@W2+b2); z=t@W3; A=z, B=z+b3 (in place) ---
__global__ __launch_bounds__(256) void k3_mid(
    float* __restrict__ A, float* __restrict__ B,
    const float* __restrict__ W2, const float* __restrict__ b2,
    const float* __restrict__ W3, const float* __restrict__ b3) {
    __shared__ float w2[NH * NH], w3[NH * NH];
    __shared__ float bb2[NH], bb3[NH];
    for (int i = threadIdx.x; i < NH * NH; i += blockDim.x) {
        w2[i] = W2[i];
        w3[i] = W3[i];
    }
    if (threadIdx.x < NH) {
        bb2[threadIdx.x] = b2[threadIdx.x];
        bb3[threadIdx.x] = b3[threadIdx.x];
    }
    __syncthreads();
    int node = blockIdx.x * blockDim.x + threadIdx.x;
    if (node >= NN) return;

    float h[NH];
    float4* Brow = (float4*)(B + (size_t)node * NH);
#pragma unroll
    for (int q = 0; q < 4; ++q) {
        float4 v = Brow[q];
        h[q * 4 + 0] = fmaxf(v.x, 0.f);
        h[q * 4 + 1] = fmaxf(v.y, 0.f);
        h[q * 4 + 2] = fmaxf(v.z, 0.f);
        h[q * 4 + 3] = fmaxf(v.w, 0.f);
    }
    float t[NH];
#pragma unroll
    for (int j = 0; j < NH; ++j) t[j] = bb2[j];
#pragma unroll
    for (int k = 0; k < NH; ++k) {
        float hk = h[k];
#pragma unroll
        for (int j = 0; j < NH; ++j) t[j] += hk * w2[k * NH + j];
    }
#pragma unroll
    for (int j = 0; j < NH; ++j) t[j] = fmaxf(t[j], 0.f);

    float z[NH];
#pragma unroll
    for (int j = 0; j < NH; ++j) z[j] = 0.f;
#pragma unroll
    for (int k = 0; k < NH; ++k) {
        float tk = t[k];
#pragma unroll
        for (int j = 0; j < NH; ++j) z[j] += tk * w3[k * NH + j];
    }
    float4* Arow = (float4*)(A + (size_t)node * NH);
#pragma unroll
    for (int q = 0; q < 4; ++q) {
        float4 a;
        a.x = z[q * 4 + 0]; a.y = z[q * 4 + 1];
        a.z = z[q * 4 + 2]; a.w = z[q * 4 + 3];
        Arow[q] = a;
        float4 bv;
        bv.x = a.x + bb3[q * 4 + 0]; bv.y = a.y + bb3[q * 4 + 1];
        bv.z = a.z + bb3[q * 4 + 2]; bv.w = a.w + bb3[q * 4 + 3];
        Brow[q] = bv;
    }
}

// ---- Kernel 5: h=relu(B); o=h@W4+b4; out = log_softmax(o) ----
__global__ __launch_bounds__(256) void k5_out(
    const float* __restrict__ B, const float* __restrict__ W4,
    const float* __restrict__ b4, float* __restrict__ out) {
    __shared__ float w4[NH * NC];
    __shared__ float bb4[NC];
    for (int i = threadIdx.x; i < NH * NC; i += blockDim.x) w4[i] = W4[i];
    if (threadIdx.x < NC) bb4[threadIdx.x] = b4[threadIdx.x];
    __syncthreads();
    int node = blockIdx.x * blockDim.x + threadIdx.x;
    if (node >= NN) return;

    float h[NH];
    const float4* Brow = (const float4*)(B + (size_t)node * NH);
#pragma unroll
    for (int q = 0; q < 4; ++q) {
        float4 v = Brow[q];
        h[q * 4 + 0] = fmaxf(v.x, 0.f);
        h[q * 4 + 1] = fmaxf(v.y, 0.f);
        h[q * 4 + 2] = fmaxf(v.z, 0.f);
        h[q * 4 + 3] = fmaxf(v.w, 0.f);
    }
    float o[NC];
#pragma unroll
    for (int c = 0; c < NC; ++c) o[c] = bb4[c];
#pragma unroll
    for (int k = 0; k < NH; ++k) {
        float hk = h[k];
#pragma unroll
        for (int c = 0; c < NC; ++c) o[c] += hk * w4[k * NC + c];
    }
    float m = o[0];
#pragma unroll
    for (int c = 1; c < NC; ++c) m = fmaxf(m, o[c]);
    float s = 0.f;
#pragma unroll
    for (int c = 0; c < NC; ++c) s += expf(o[c] - m);
    float ls = m + logf(s);
    float* op = out + (size_t)node * NC;
#pragma unroll
    for (int c = 0; c < NC; ++c) op[c] = o[c] - ls;
}

extern "C" void kernel_launch(void* const* d_in, const int* in_sizes, int n_in,
                              void* d_out, int out_size, void* d_ws, size_t ws_size,
                              hipStream_t stream) {
    const float* x  = (const float*)d_in[0];
    const int*   ei = (const int*)d_in[1];   // [2, NE] flat: src then dst
    const float* W1 = (const float*)d_in[2];
    const float* b1 = (const float*)d_in[3];
    const float* W2 = (const float*)d_in[4];
    const float* b2 = (const float*)d_in[5];
    const float* W3 = (const float*)d_in[6];
    const float* b3 = (const float*)d_in[7];
    const float* W4 = (const float*)d_in[8];
    const float* b4 = (const float*)d_in[9];
    float* out = (float*)d_out;

    const int* src = ei;
    const int* dst = ei + NE;

    // workspace layout (all 16B-aligned: counts are multiples of 4)
    float* A   = (float*)d_ws;                        // [NN, NH]
    float* B   = A + (size_t)NN * NH;                 // [NN, NH]
    int*   deg = (int*)(B + (size_t)NN * NH);         // [NN]
    int*   incl= deg + NN;                            // [NN]
    int*   off = incl + NN;                           // [NN]
    int*   cur = off + NN;                            // [NN]
    int*   csr = cur + NN;                            // [NE]
    int*   bsum= csr + NE;                            // [512]
    int*   boff= bsum + 512;                          // [512]

    const int nodeBlocks  = (NN + 255) / 256;
    const int edgeBlocks  = (NE + 255) / 256;
    const int gatherBlocks= (NN * 4 + 255) / 256;

    hipMemsetAsync(deg, 0, (size_t)NN * sizeof(int), stream);
    k1_gemm<<<nodeBlocks, 256, 0, stream>>>(x, W1, b1, A, B);

    // build CSR (by dst) once; reused by both aggregation passes
    k_deg<<<edgeBlocks, 256, 0, stream>>>(dst, deg);
    k_scan_part<<<SCAN_B, 256, 0, stream>>>(deg, incl, bsum);
    k_scan_block<<<1, 512, 0, stream>>>(bsum, boff);
    k_scan_final<<<SCAN_B, 256, 0, stream>>>(incl, deg, boff, off, cur);
    k_fill<<<edgeBlocks, 256, 0, stream>>>(src, dst, cur, csr);

    // conv1 aggregation + MLP
    k_gather<<<gatherBlocks, 256, 0, stream>>>(A, B, off, deg, csr);
    k3_mid<<<nodeBlocks, 256, 0, stream>>>(A, B, W2, b2, W3, b3);

    // conv2 aggregation + head
    k_gather<<<gatherBlocks, 256, 0, stream>>>(A, B, off, deg, csr);
    k5_out<<<nodeBlocks, 256, 0, stream>>>(B, W4, b4, out);
}